// Round 2
// baseline (237.675 us; speedup 1.0000x reference)
//
#include <hip/hip_runtime.h>
#include <hip/hip_bf16.h>

typedef __hip_bfloat16 bf16;

#define L_    1024
#define C_    16
#define US_   32
#define HID_  128
#define TI1   32
#define TI2   16

__device__ __forceinline__ float b2f(bf16 v) { return __bfloat162float(v); }

// Flag-dispatched load: data is either bf16 or fp32, decided at runtime.
__device__ __forceinline__ float LD(const void* p, int i, bool f32) {
  return f32 ? reinterpret_cast<const float*>(p)[i]
             : b2f(reinterpret_cast<const bf16*>(p)[i]);
}

// Overflow-safe tanh: never produces NaN/inf even for huge |x|.
__device__ __forceinline__ float tanh_s(float x) {
  float ax = fabsf(x);
  float t  = __expf(-2.0f * ax);          // in (0,1], underflows to 0 for big ax
  float r  = (1.0f - t) / (1.0f + t);
  return copysignf(r, x);
}

// ---- dtype detector: if the buffer viewed as bf16 contains |v|>1e6 or NaN,
// the underlying data must be fp32 (mantissa halves look like random exps).
__global__ void detect_kernel(const bf16* __restrict__ x, int n, int* flag) {
  __shared__ int bad[256];
  int tid = threadIdx.x;
  int b = 0;
  for (int i = tid; i < n; i += 256) {
    float v = b2f(x[i]);
    if (!(fabsf(v) <= 1.0e6f)) b = 1;     // catches huge AND NaN
  }
  bad[tid] = b;
  __syncthreads();
  for (int s = 128; s; s >>= 1) {
    if (tid < s) bad[tid] |= bad[tid + s];
    __syncthreads();
  }
  if (tid == 0) *flag = bad[0];
}

struct BranchP {
  const void *x, *Wt, *Wx, *bh, *Wa, *ba, *g1, *be1, *W1, *b1, *W2, *b2, *g2, *be2;
  float* y;
};

// One block: (branch, batch, 32-row i-tile). Fused: self-attn(band) + LN + FF + LN.
__global__ __launch_bounds__(256) void branch_kernel(BranchP P1, BranchP P2,
                                                     const int* __restrict__ flag) {
  const bool f32 = (*flag != 0);
  const BranchP P = blockIdx.z ? P2 : P1;
  const int b   = blockIdx.y;
  const int i0  = blockIdx.x * TI1;
  const int tid = threadIdx.x;
  const int j0  = max(0, i0 - 63);
  const int j1  = min(L_, i0 + TI1 + 64);
  const int Wd  = j1 - j0;               // <= 159

  __shared__ float xs[C_][161];          // x[c][j-j0]
  __shared__ union {
    struct { float ks[160][33]; float qs[TI1][33]; } a;          // phases 1-2
    struct { float W1s[C_][129]; float W2s[HID_][17]; float b1s[HID_]; } bb; // phases 3+
  } ovl;
  __shared__ float es[TI1][129];         // e / exp(e) ; reused as h[128] in FF
  __shared__ float ya[TI1][17];          // post-LN1 activations
  __shared__ float Wts[C_][US_], Wxs[C_][US_];
  __shared__ float Was[US_], bhs[US_];
  __shared__ float g1s[C_], be1s[C_], b2s[C_], g2s[C_], be2s[C_];
  __shared__ float sinv[TI1];
  __shared__ float bas;

  // ---- P0: load small weights + x slice ----
  for (int idx = tid; idx < C_ * US_; idx += 256) {
    int c = idx >> 5, u = idx & 31;
    Wts[c][u] = LD(P.Wt, idx, f32);
    Wxs[c][u] = LD(P.Wx, idx, f32);
  }
  if (tid < US_) { Was[tid] = LD(P.Wa, tid, f32); bhs[tid] = LD(P.bh, tid, f32); }
  if (tid < C_) {
    g1s[tid] = LD(P.g1, tid, f32); be1s[tid] = LD(P.be1, tid, f32);
    g2s[tid] = LD(P.g2, tid, f32); be2s[tid] = LD(P.be2, tid, f32);
    b2s[tid] = LD(P.b2, tid, f32);
  }
  if (tid == 0) bas = LD(P.ba, 0, f32);
  for (int idx = tid; idx < C_ * Wd; idx += 256) {
    int c = idx / Wd, jj = idx - c * Wd;
    xs[c][jj] = LD(P.x, (b * C_ + c) * L_ + j0 + jj, f32);
  }
  __syncthreads();

  // ---- P1: k (with bh folded) and q ----
  for (int idx = tid; idx < Wd * US_; idx += 256) {
    int j = idx >> 5, u = idx & 31;
    float a = bhs[u];
#pragma unroll
    for (int c = 0; c < C_; ++c) a += xs[c][j] * Wxs[c][u];
    ovl.a.ks[j][u] = a;
  }
  for (int idx = tid; idx < TI1 * US_; idx += 256) {
    int il = idx >> 5, u = idx & 31;
    float a = 0.f;
#pragma unroll
    for (int c = 0; c < C_; ++c) a += xs[c][i0 - j0 + il] * Wts[c][u];
    ovl.a.qs[il][u] = a;
  }
  __syncthreads();

  const int il  = tid >> 3, sub = tid & 7;   // 32 rows x 8 lanes
  const int ig  = i0 + il;
  const int jlo = max(0, ig - 63), jhi = min(L_, ig + 65);
  const int nj  = jhi - jlo;                 // 65..128
  const int jb  = jlo - j0;

  // ---- P2: band scores e = tanh(q+k+bh)@Wa + ba ; softmax with EPS ----
  {
    float qreg[US_];
#pragma unroll
    for (int u = 0; u < US_; ++u) qreg[u] = ovl.a.qs[il][u];
    float mx = -1e30f;
    for (int jj = sub; jj < nj; jj += 8) {
      const float* kr = ovl.a.ks[jb + jj];
      float acc = bas;
#pragma unroll
      for (int u = 0; u < US_; ++u) acc += tanh_s(qreg[u] + kr[u]) * Was[u];
      es[il][jj] = acc;
      mx = fmaxf(mx, acc);
    }
#pragma unroll
    for (int m = 4; m; m >>= 1) mx = fmaxf(mx, __shfl_xor(mx, m));
    float s = 0.f;
    for (int jj = sub; jj < nj; jj += 8) {
      float v = __expf(es[il][jj] - mx);
      es[il][jj] = v;
      s += v;
    }
#pragma unroll
    for (int m = 4; m; m >>= 1) s += __shfl_xor(s, m);
    if (sub == 0) sinv[il] = 1.0f / (s + 1e-5f);
  }
  __syncthreads();

  // ---- P3: load FF weights into dead k/q region; v = a@x ; residual ; LN1 ----
  for (int idx = tid; idx < C_ * HID_; idx += 256) {
    ovl.bb.W1s[idx >> 7][idx & 127] = LD(P.W1, idx, f32);
    ovl.bb.W2s[idx >> 4][idx & 15]  = LD(P.W2, idx, f32);
  }
  if (tid < HID_) ovl.bb.b1s[tid] = LD(P.b1, tid, f32);
  {
    float inv = sinv[il];
    float v0 = 0.f, v1 = 0.f;
    for (int jj = 0; jj < nj; ++jj) {
      float a = es[il][jj];
      v0 += a * xs[sub][jb + jj];
      v1 += a * xs[sub + 8][jb + jj];
    }
    float y0 = xs[sub][ig - j0] + v0 * inv;
    float y1 = xs[sub + 8][ig - j0] + v1 * inv;
    float s1 = y0 + y1, s2 = y0 * y0 + y1 * y1;
#pragma unroll
    for (int m = 4; m; m >>= 1) { s1 += __shfl_xor(s1, m); s2 += __shfl_xor(s2, m); }
    float mean = s1 * (1.f / 16.f);
    float var  = s2 * (1.f / 16.f) - mean * mean;
    float rstd = rsqrtf(fmaxf(var, 0.f) + 1e-14f);
    ya[il][sub]     = (y0 - mean) * rstd * g1s[sub]     + be1s[sub];
    ya[il][sub + 8] = (y1 - mean) * rstd * g1s[sub + 8] + be1s[sub + 8];
  }
  __syncthreads();

  // ---- P4: FF hidden h = relu(y@W1 + b1) -> es reused as h ----
  {
    float yc[C_];
#pragma unroll
    for (int c = 0; c < C_; ++c) yc[c] = ya[il][c];
#pragma unroll
    for (int t = 0; t < 16; ++t) {
      int u = sub + 8 * t;
      float a = ovl.bb.b1s[u];
#pragma unroll
      for (int c = 0; c < C_; ++c) a += yc[c] * ovl.bb.W1s[c][u];
      es[il][u] = fmaxf(a, 0.f);
    }
  }
  __syncthreads();

  // ---- P5: FF out + residual + LN2 -> write fp32 y ----
  {
    float o0 = b2s[sub], o1 = b2s[sub + 8];
    for (int u = 0; u < HID_; ++u) {
      float h = es[il][u];
      o0 += h * ovl.bb.W2s[u][sub];
      o1 += h * ovl.bb.W2s[u][sub + 8];
    }
    float y0 = ya[il][sub] + o0;
    float y1 = ya[il][sub + 8] + o1;
    float s1 = y0 + y1, s2 = y0 * y0 + y1 * y1;
#pragma unroll
    for (int m = 4; m; m >>= 1) { s1 += __shfl_xor(s1, m); s2 += __shfl_xor(s2, m); }
    float mean = s1 * (1.f / 16.f);
    float var  = s2 * (1.f / 16.f) - mean * mean;
    float rstd = rsqrtf(fmaxf(var, 0.f) + 1e-14f);
    P.y[(b * C_ + sub) * L_ + ig]       = (y0 - mean) * rstd * g2s[sub]     + be2s[sub];
    P.y[(b * C_ + sub + 8) * L_ + ig]   = (y1 - mean) * rstd * g2s[sub + 8] + be2s[sub + 8];
  }
}

// One block: (batch, 16-row i-tile). Cross-attn(band) + LN + FF + LN -> out.
__global__ __launch_bounds__(256) void cross_kernel(
    const float* __restrict__ y1g, const float* __restrict__ y2g,
    const void* Wq, const void* Wk, const void* Wv,
    const void* g1, const void* be1, const void* W1, const void* b1,
    const void* W2, const void* b2, const void* g2, const void* be2,
    void* out, const int* __restrict__ flag) {
  const bool f32 = (*flag != 0);
  const int b   = blockIdx.y;
  const int i0  = blockIdx.x * TI2;
  const int tid = threadIdx.x;
  const int j0  = max(0, i0 - 63);
  const int j1  = min(L_, i0 + TI2 + 64);
  const int Wd  = j1 - j0;               // <= 143

  __shared__ float y1s[C_][TI2 + 1];
  __shared__ float y2s[C_][145];
  __shared__ float ks[144][17], vs[144][17];
  __shared__ float qs[TI2][17];
  __shared__ float es[TI2][129];         // scores; reused as h[128]
  __shared__ float ya[TI2][17];
  __shared__ float Wqs[C_][C_], Wks[C_][C_], Wvs[C_][C_];
  __shared__ float W1s[C_][129];
  __shared__ float W2s[HID_][17];
  __shared__ float b1s[HID_];
  __shared__ float g1s[C_], be1s[C_], b2s[C_], g2s[C_], be2s[C_];
  __shared__ float sinv[TI2];

  for (int idx = tid; idx < C_ * C_; idx += 256) {
    int c = idx >> 4, u = idx & 15;
    Wqs[c][u] = LD(Wq, idx, f32); Wks[c][u] = LD(Wk, idx, f32); Wvs[c][u] = LD(Wv, idx, f32);
  }
  for (int idx = tid; idx < C_ * HID_; idx += 256) {
    W1s[idx >> 7][idx & 127] = LD(W1, idx, f32);
    W2s[idx >> 4][idx & 15]  = LD(W2, idx, f32);
  }
  if (tid < HID_) b1s[tid] = LD(b1, tid, f32);
  if (tid < C_) {
    g1s[tid] = LD(g1, tid, f32); be1s[tid] = LD(be1, tid, f32);
    g2s[tid] = LD(g2, tid, f32); be2s[tid] = LD(be2, tid, f32);
    b2s[tid] = LD(b2, tid, f32);
  }
  for (int idx = tid; idx < C_ * TI2; idx += 256) {
    int c = idx >> 4, i = idx & 15;
    y1s[c][i] = y1g[(b * C_ + c) * L_ + i0 + i];
  }
  for (int idx = tid; idx < C_ * Wd; idx += 256) {
    int c = idx / Wd, jj = idx - c * Wd;
    y2s[c][jj] = y2g[(b * C_ + c) * L_ + j0 + jj];
  }
  __syncthreads();

  // q, k, v projections
  for (int idx = tid; idx < TI2 * C_; idx += 256) {
    int i = idx >> 4, u = idx & 15;
    float a = 0.f;
#pragma unroll
    for (int c = 0; c < C_; ++c) a += y1s[c][i] * Wqs[c][u];
    qs[i][u] = a;
  }
  for (int idx = tid; idx < Wd * C_; idx += 256) {
    int j = idx >> 4, u = idx & 15;
    float ak = 0.f, av = 0.f;
#pragma unroll
    for (int c = 0; c < C_; ++c) { float y = y2s[c][j]; ak += y * Wks[c][u]; av += y * Wvs[c][u]; }
    ks[j][u] = ak; vs[j][u] = av;
  }
  __syncthreads();

  const int il  = tid >> 4, sub = tid & 15;  // 16 rows x 16 lanes
  const int ig  = i0 + il;
  const int jlo = max(0, ig - 63), jhi = min(L_, ig + 65);
  const int nj  = jhi - jlo;
  const int jb  = jlo - j0;

  // band scores + exact softmax
  {
    float qreg[C_];
#pragma unroll
    for (int u = 0; u < C_; ++u) qreg[u] = qs[il][u];
    float mx = -1e30f;
    for (int jj = sub; jj < nj; jj += 16) {
      const float* kr = ks[jb + jj];
      float acc = 0.f;
#pragma unroll
      for (int u = 0; u < C_; ++u) acc += qreg[u] * kr[u];
      acc *= 0.25f;                        // 1/sqrt(16)
      es[il][jj] = acc;
      mx = fmaxf(mx, acc);
    }
#pragma unroll
    for (int m = 8; m; m >>= 1) mx = fmaxf(mx, __shfl_xor(mx, m));
    float s = 0.f;
    for (int jj = sub; jj < nj; jj += 16) {
      float v = __expf(es[il][jj] - mx);
      es[il][jj] = v; s += v;
    }
#pragma unroll
    for (int m = 8; m; m >>= 1) s += __shfl_xor(s, m);
    if (sub == 0) sinv[il] = 1.0f / s;
  }
  __syncthreads();

  // attn out + residual + LN1
  {
    float inv = sinv[il];
    float acc = 0.f;
    for (int jj = 0; jj < nj; ++jj) acc += es[il][jj] * vs[jb + jj][sub];
    float y0 = y1s[sub][il] + acc * inv;
    float s1 = y0, s2 = y0 * y0;
#pragma unroll
    for (int m = 8; m; m >>= 1) { s1 += __shfl_xor(s1, m); s2 += __shfl_xor(s2, m); }
    float mean = s1 * (1.f / 16.f);
    float var  = s2 * (1.f / 16.f) - mean * mean;
    float rstd = rsqrtf(fmaxf(var, 0.f) + 1e-14f);
    ya[il][sub] = (y0 - mean) * rstd * g1s[sub] + be1s[sub];
  }
  __syncthreads();

  // FF hidden
  {
    float yc[C_];
#pragma unroll
    for (int c = 0; c < C_; ++c) yc[c] = ya[il][c];
#pragma unroll
    for (int t = 0; t < 8; ++t) {
      int u = sub + 16 * t;
      float a = b1s[u];
#pragma unroll
      for (int c = 0; c < C_; ++c) a += yc[c] * W1s[c][u];
      es[il][u] = fmaxf(a, 0.f);
    }
  }
  __syncthreads();

  // FF out + residual + LN2 -> out (flag-dispatched dtype)
  {
    float o = b2s[sub];
    for (int u = 0; u < HID_; ++u) o += es[il][u] * W2s[u][sub];
    float y0 = ya[il][sub] + o;
    float s1 = y0, s2 = y0 * y0;
#pragma unroll
    for (int m = 8; m; m >>= 1) { s1 += __shfl_xor(s1, m); s2 += __shfl_xor(s2, m); }
    float mean = s1 * (1.f / 16.f);
    float var  = s2 * (1.f / 16.f) - mean * mean;
    float rstd = rsqrtf(fmaxf(var, 0.f) + 1e-14f);
    float r = (y0 - mean) * rstd * g2s[sub] + be2s[sub];
    int oi = (b * C_ + sub) * L_ + ig;
    if (f32) reinterpret_cast<float*>(out)[oi] = r;
    else     reinterpret_cast<bf16*>(out)[oi] = __float2bfloat16(r);
  }
}

extern "C" void kernel_launch(void* const* d_in, const int* in_sizes, int n_in,
                              void* d_out, int out_size, void* d_ws, size_t ws_size,
                              hipStream_t stream) {
  (void)n_in; (void)out_size; (void)ws_size;
  const void* const* in = reinterpret_cast<const void* const*>(d_in);
  int*   flag = reinterpret_cast<int*>(d_ws);
  float* y1w  = reinterpret_cast<float*>(reinterpret_cast<char*>(d_ws) + 256);
  float* y2w  = y1w + 4 * C_ * L_;

  detect_kernel<<<1, 256, 0, stream>>>(
      reinterpret_cast<const bf16*>(d_in[0]), in_sizes[0], flag);

  BranchP P1 { in[0],  in[2],  in[3],  in[4],  in[5],  in[6],  in[7],
               in[8],  in[9],  in[10], in[11], in[12], in[13], in[14], y1w };
  BranchP P2 { in[1],  in[15], in[16], in[17], in[18], in[19], in[20],
               in[21], in[22], in[23], in[24], in[25], in[26], in[27], y2w };

  branch_kernel<<<dim3(L_ / TI1, 4, 2), 256, 0, stream>>>(P1, P2, flag);
  cross_kernel<<<dim3(L_ / TI2, 4), 256, 0, stream>>>(
      y1w, y2w, in[28], in[29], in[30],
      in[31], in[32], in[33], in[34], in[35], in[36], in[37], in[38],
      d_out, flag);
}

// Round 7
// 170.823 us; speedup vs baseline: 1.3914x; 1.3914x over previous
//
#include <hip/hip_runtime.h>
#include <hip/hip_bf16.h>

// All inputs AND output are float32 (proven: round-2 runtime-dispatch passed on
// the fp32 path; hard-coded bf16 reads NaN'd in rounds 1/4/5/6).

#define L_    1024
#define C_    16
#define US_   32
#define HID_  128
#define TI1   16
#define TI2   16

struct BranchP {
  const float *x, *Wt, *Wx, *bh, *Wa, *ba, *g1, *be1, *W1, *b1, *W2, *b2, *g2, *be2;
  float* y;   // out: [4][1024][16] fp32, position-major
};

// One block: (branch, batch, 16-row i-tile). Self-attn(band) + LN + FF + LN.
__global__ __launch_bounds__(256) void branch_kernel(BranchP Pa, BranchP Pb) {
  const BranchP P = blockIdx.z ? Pb : Pa;
  const int b   = blockIdx.y;
  const int i0  = blockIdx.x * TI1;
  const int tid = threadIdx.x;
  const int j0  = max(0, i0 - 63);
  const int j1  = min(L_, i0 + TI1 + 64);
  const int Wd  = j1 - j0;               // <= 143

  __shared__ float xs[C_][145];          // x[c][j-j0]
  __shared__ union {
    struct { float ks[144][33]; float qs[TI1][33]; } a;                       // P1-P2
    struct { float W1s[C_][129]; float W2s[HID_][17]; float b1s[HID_]; } bb;  // P3+
  } ovl;
  __shared__ float es[TI1][129];
  __shared__ float ya[TI1][17];
  __shared__ float Wts[C_][US_], Wxs[C_][US_];   // pre-scaled by 2.0 (exact)
  __shared__ float m2was[US_], bhs[US_];         // -2*Wa ; 2*bh
  __shared__ float g1s[C_], be1s[C_], b2s[C_], g2s[C_], be2s[C_];
  __shared__ float bas;

  // ---- P0: weights + x slice ----
  for (int idx = tid; idx < C_ * US_; idx += 256) {
    int c = idx >> 5, u = idx & 31;
    Wts[c][u] = 2.0f * P.Wt[idx];
    Wxs[c][u] = 2.0f * P.Wx[idx];
  }
  if (tid < US_) { m2was[tid] = -2.0f * P.Wa[tid]; bhs[tid] = 2.0f * P.bh[tid]; }
  if (tid < C_) {
    g1s[tid] = P.g1[tid]; be1s[tid] = P.be1[tid];
    g2s[tid] = P.g2[tid]; be2s[tid] = P.be2[tid];
    b2s[tid] = P.b2[tid];
  }
  if (tid == 0) bas = P.ba[0];
  for (int idx = tid; idx < C_ * Wd; idx += 256) {
    int c = idx / Wd, jj = idx - c * Wd;
    xs[c][jj] = P.x[(b * C_ + c) * L_ + j0 + jj];
  }
  __syncthreads();

  // ---- P1: k = 2*(x@Wx + bh), q = 2*(x@Wt) ----
  for (int idx = tid; idx < Wd * US_; idx += 256) {
    int j = idx >> 5, u = idx & 31;
    float a = bhs[u];
#pragma unroll
    for (int c = 0; c < C_; ++c) a = fmaf(xs[c][j], Wxs[c][u], a);
    ovl.a.ks[j][u] = a;
  }
  for (int idx = tid; idx < TI1 * US_; idx += 256) {
    int i = idx >> 5, u = idx & 31;
    float a = 0.f;
#pragma unroll
    for (int c = 0; c < C_; ++c) a = fmaf(xs[c][i0 - j0 + i], Wts[c][u], a);
    ovl.a.qs[i][u] = a;
  }
  __syncthreads();

  const int il  = tid >> 4, sub = tid & 15;  // 16 rows x 16 lanes
  const int ig  = i0 + il;
  const int jlo = max(0, ig - 63), jhi = min(L_, ig + 65);
  const int nj  = jhi - jlo;                 // 64..128
  const int jb  = jlo - j0;

  // ---- P2: e = ba + sum_u Wa[u]*tanh(q+k+bh) ; tanh = 1 - 2/(1+e^{2x}) ----
  float inv;
  {
    float xq[US_];
#pragma unroll
    for (int u = 0; u < US_; ++u) xq[u] = ovl.a.qs[il][u];
    float eacc = bas;                       // ba + sum(Wa), per-thread
#pragma unroll
    for (int u = 0; u < US_; ++u) eacc -= 0.5f * m2was[u];
    float mx = -1e30f;
    for (int jj = sub; jj < nj; jj += 16) {
      const float* kr = ovl.a.ks[jb + jj];
      float acc = eacc;
#pragma unroll
      for (int u = 0; u < US_; ++u) {
        float t = __expf(xq[u] + kr[u]);    // e^{2(q+k+bh)} ; inf-safe
        acc = fmaf(m2was[u], 1.0f / (1.0f + t), acc);
      }
      es[il][jj] = acc;
      mx = fmaxf(mx, acc);
    }
#pragma unroll
    for (int m = 8; m; m >>= 1) mx = fmaxf(mx, __shfl_xor(mx, m));
    float s = 0.f;
    for (int jj = sub; jj < nj; jj += 16) {
      float v = __expf(es[il][jj] - mx);
      es[il][jj] = v; s += v;
    }
#pragma unroll
    for (int m = 8; m; m >>= 1) s += __shfl_xor(s, m);
    inv = 1.0f / (s + 1e-5f);
  }
  __syncthreads();

  // ---- P3: FF weights into dead union; v = a@x ; residual ; LN1 ----
  for (int idx = tid; idx < C_ * HID_; idx += 256) {
    ovl.bb.W1s[idx >> 7][idx & 127] = P.W1[idx];
    ovl.bb.W2s[idx >> 4][idx & 15]  = P.W2[idx];
  }
  if (tid < HID_) ovl.bb.b1s[tid] = P.b1[tid];
  float yln;
  {
    float v0 = 0.f;
    for (int jj = 0; jj < nj; ++jj) v0 = fmaf(es[il][jj], xs[sub][jb + jj], v0);
    float y0 = xs[sub][ig - j0] + v0 * inv;
    float s1 = y0, s2 = y0 * y0;
#pragma unroll
    for (int m = 8; m; m >>= 1) { s1 += __shfl_xor(s1, m); s2 += __shfl_xor(s2, m); }
    float mean = s1 * (1.f / 16.f);
    float var  = s2 * (1.f / 16.f) - mean * mean;
    float rstd = rsqrtf(fmaxf(var, 0.f) + 1e-14f);
    yln = (y0 - mean) * rstd * g1s[sub] + be1s[sub];
    ya[il][sub] = yln;
  }
  __syncthreads();

  // ---- P4: h = relu(y@W1 + b1) ----
  {
    float yc[C_];
#pragma unroll
    for (int c = 0; c < C_; ++c) yc[c] = ya[il][c];
#pragma unroll
    for (int t = 0; t < 8; ++t) {
      int u = sub + 16 * t;
      float a = ovl.bb.b1s[u];
#pragma unroll
      for (int c = 0; c < C_; ++c) a = fmaf(yc[c], ovl.bb.W1s[c][u], a);
      es[il][u] = fmaxf(a, 0.f);
    }
  }
  __syncthreads();

  // ---- P5: FF out + residual + LN2 -> fp32 y [b][i][c] ----
  {
    float o = b2s[sub];
    for (int u = 0; u < HID_; ++u) o = fmaf(es[il][u], ovl.bb.W2s[u][sub], o);
    float y0 = yln + o;
    float s1 = y0, s2 = y0 * y0;
#pragma unroll
    for (int m = 8; m; m >>= 1) { s1 += __shfl_xor(s1, m); s2 += __shfl_xor(s2, m); }
    float mean = s1 * (1.f / 16.f);
    float var  = s2 * (1.f / 16.f) - mean * mean;
    float rstd = rsqrtf(fmaxf(var, 0.f) + 1e-14f);
    P.y[(b * L_ + ig) * C_ + sub] = (y0 - mean) * rstd * g2s[sub] + be2s[sub];
  }
}

// Cross-attn via M = Wq*Wk^T fusion: score = y1^T M y2 ; out = (a@y2^T)@Wv.
__global__ __launch_bounds__(256) void cross_kernel(
    const float* __restrict__ y1g, const float* __restrict__ y2g,
    const float* Wq, const float* Wk, const float* Wv,
    const float* g1, const float* be1, const float* W1, const float* b1,
    const float* W2, const float* b2, const float* g2, const float* be2,
    float* out) {
  const int b   = blockIdx.y;
  const int i0  = blockIdx.x * TI2;
  const int tid = threadIdx.x;
  const int j0  = max(0, i0 - 63);
  const int j1  = min(L_, i0 + TI2 + 64);
  const int Wd  = j1 - j0;               // <= 143

  __shared__ float y1s[TI2][17];
  __shared__ float y2s[144][17];
  __shared__ float Ms[C_][17];
  __shared__ float zs[TI2][17];          // z = 0.25*(Wq Wk^T)^T-applied y1 ; reused as wv
  __shared__ float es[TI2][129];
  __shared__ float ya[TI2][17];
  __shared__ float Wqs[C_][C_], Wks[C_][C_], Wvs[C_][C_];
  __shared__ float W1s[C_][129], W2s[HID_][17], b1s[HID_];
  __shared__ float g1s[C_], be1s[C_], b2s[C_], g2s[C_], be2s[C_];

  // ---- P0 ----
  {
    int c = tid >> 4, u = tid & 15;
    Wqs[c][u] = Wq[tid]; Wks[c][u] = Wk[tid]; Wvs[c][u] = Wv[tid];
    y1s[c][u] = y1g[(b * L_ + i0 + c) * C_ + u];   // c is row i here
  }
  for (int idx = tid; idx < C_ * HID_; idx += 256) {
    W1s[idx >> 7][idx & 127] = W1[idx];
    W2s[idx >> 4][idx & 15]  = W2[idx];
  }
  if (tid < HID_) b1s[tid] = b1[tid];
  if (tid < C_) {
    g1s[tid] = g1[tid]; be1s[tid] = be1[tid];
    g2s[tid] = g2[tid]; be2s[tid] = be2[tid];
    b2s[tid] = b2[tid];
  }
  for (int idx = tid; idx < Wd * C_; idx += 256) {
    int jj = idx >> 4, c = idx & 15;
    y2s[jj][c] = y2g[(b * L_ + j0 + jj) * C_ + c];
  }
  __syncthreads();

  // ---- P1a: M = 0.25 * Wq Wk^T ----
  {
    int c1 = tid >> 4, c2 = tid & 15;
    float m = 0.f;
#pragma unroll
    for (int u = 0; u < C_; ++u) m = fmaf(Wqs[c1][u], Wks[c2][u], m);
    Ms[c1][c2] = 0.25f * m;
  }
  __syncthreads();
  // ---- P1b: z[i][c] = sum_c' y1[i][c'] M[c'][c] ----
  {
    int i = tid >> 4, c = tid & 15;
    float z = 0.f;
#pragma unroll
    for (int cc = 0; cc < C_; ++cc) z = fmaf(y1s[i][cc], Ms[cc][c], z);
    zs[i][c] = z;
  }
  __syncthreads();

  const int il  = tid >> 4, sub = tid & 15;
  const int ig  = i0 + il;
  const int jlo = max(0, ig - 63), jhi = min(L_, ig + 65);
  const int nj  = jhi - jlo;
  const int jb  = jlo - j0;

  // ---- P2: scores + exact softmax ----
  float inv;
  {
    float zr[C_];
#pragma unroll
    for (int c = 0; c < C_; ++c) zr[c] = zs[il][c];
    float mx = -1e30f;
    for (int jj = sub; jj < nj; jj += 16) {
      const float* yr = y2s[jb + jj];
      float a = 0.f;
#pragma unroll
      for (int c = 0; c < C_; ++c) a = fmaf(zr[c], yr[c], a);
      es[il][jj] = a;
      mx = fmaxf(mx, a);
    }
#pragma unroll
    for (int m = 8; m; m >>= 1) mx = fmaxf(mx, __shfl_xor(mx, m));
    float s = 0.f;
    for (int jj = sub; jj < nj; jj += 16) {
      float v = __expf(es[il][jj] - mx);
      es[il][jj] = v; s += v;
    }
#pragma unroll
    for (int m = 8; m; m >>= 1) s += __shfl_xor(s, m);
    inv = 1.0f / s;
  }
  __syncthreads();

  // ---- P3: wv[c] = (sum_j a_j y2[j][c]) / s ----
  {
    float w = 0.f;
    for (int jj = 0; jj < nj; ++jj) w = fmaf(es[il][jj], y2s[jb + jj][sub], w);
    zs[il][sub] = w * inv;
  }
  __syncthreads();

  // ---- P4: attn = wv@Wv ; residual ; LN1 ----
  float yln;
  {
    float a = 0.f;
#pragma unroll
    for (int c = 0; c < C_; ++c) a = fmaf(zs[il][c], Wvs[c][sub], a);
    float y0 = y1s[il][sub] + a;
    float s1 = y0, s2 = y0 * y0;
#pragma unroll
    for (int m = 8; m; m >>= 1) { s1 += __shfl_xor(s1, m); s2 += __shfl_xor(s2, m); }
    float mean = s1 * (1.f / 16.f);
    float var  = s2 * (1.f / 16.f) - mean * mean;
    float rstd = rsqrtf(fmaxf(var, 0.f) + 1e-14f);
    yln = (y0 - mean) * rstd * g1s[sub] + be1s[sub];
    ya[il][sub] = yln;
  }
  __syncthreads();

  // ---- P5: FF hidden ----
  {
    float yc[C_];
#pragma unroll
    for (int c = 0; c < C_; ++c) yc[c] = ya[il][c];
#pragma unroll
    for (int t = 0; t < 8; ++t) {
      int u = sub + 16 * t;
      float a = b1s[u];
#pragma unroll
      for (int c = 0; c < C_; ++c) a = fmaf(yc[c], W1s[c][u], a);
      es[il][u] = fmaxf(a, 0.f);
    }
  }
  __syncthreads();

  // ---- P6: FF out + residual + LN2 -> es[i][c] ----
  {
    float o = b2s[sub];
    for (int u = 0; u < HID_; ++u) o = fmaf(es[il][u], W2s[u][sub], o);
    float y0 = yln + o;
    float s1 = y0, s2 = y0 * y0;
#pragma unroll
    for (int m = 8; m; m >>= 1) { s1 += __shfl_xor(s1, m); s2 += __shfl_xor(s2, m); }
    float mean = s1 * (1.f / 16.f);
    float var  = s2 * (1.f / 16.f) - mean * mean;
    float rstd = rsqrtf(fmaxf(var, 0.f) + 1e-14f);
    es[il][sub] = (y0 - mean) * rstd * g2s[sub] + be2s[sub];
  }
  __syncthreads();

  // ---- P7: transposed coalesced fp32 store [B][C][L] ----
  {
    int c = tid >> 4, i = tid & 15;
    out[(b * C_ + c) * L_ + i0 + i] = es[i][c];
  }
}

extern "C" void kernel_launch(void* const* d_in, const int* in_sizes, int n_in,
                              void* d_out, int out_size, void* d_ws, size_t ws_size,
                              hipStream_t stream) {
  (void)in_sizes; (void)n_in; (void)out_size; (void)ws_size;
  const float* const* in = reinterpret_cast<const float* const*>(d_in);
  float* y1w = reinterpret_cast<float*>(d_ws);
  float* y2w = y1w + 4 * L_ * C_;

  BranchP Pa { in[0],  in[2],  in[3],  in[4],  in[5],  in[6],  in[7],
               in[8],  in[9],  in[10], in[11], in[12], in[13], in[14], y1w };
  BranchP Pb { in[1],  in[15], in[16], in[17], in[18], in[19], in[20],
               in[21], in[22], in[23], in[24], in[25], in[26], in[27], y2w };

  branch_kernel<<<dim3(L_ / TI1, 4, 2), 256, 0, stream>>>(Pa, Pb);
  cross_kernel<<<dim3(L_ / TI2, 4), 256, 0, stream>>>(
      y1w, y2w, in[28], in[29], in[30],
      in[31], in[32], in[33], in[34], in[35], in[36], in[37], in[38],
      reinterpret_cast<float*>(d_out));
}